// Round 3
// baseline (337.829 us; speedup 1.0000x reference)
//
#include <hip/hip_runtime.h>

typedef unsigned short u16;
typedef unsigned int u32;
typedef unsigned long long u64;
typedef __bf16 bf16x8 __attribute__((ext_vector_type(8)));
typedef float f32x4 __attribute__((ext_vector_type(4)));

#define B_  4
#define T_  2048
#define C_  1024
#define NH_ 16
#define D_  64
#define M_  (B_*T_)          // 8192
#define N_QKV (3*C_)         // 3072

#define ATTN_BLOCKS 1024     // one block per item, 4 blocks/CU (36KB LDS)

// raw barrier + static waitcnt (no vmcnt(0) drain -- keeps prefetch in flight)
#define BARRIER()  __asm__ __volatile__("s_barrier" ::: "memory")
#define WAIT_VM4() __asm__ __volatile__("s_waitcnt vmcnt(4)" ::: "memory")
#define WAIT_VM8() __asm__ __volatile__("s_waitcnt vmcnt(8)" ::: "memory")
#define WAIT_VM0() __asm__ __volatile__("s_waitcnt vmcnt(0)" ::: "memory")
#define LGKM0()    __asm__ __volatile__("s_waitcnt lgkmcnt(0)" ::: "memory")

// async global->LDS, 16B per lane. LDS dest = wave-uniform base + lane*16
__device__ __forceinline__ void async_copy16(void* lds, const void* gptr) {
  __builtin_amdgcn_global_load_lds(
      (const __attribute__((address_space(1))) u32*)gptr,
      (__attribute__((address_space(3))) u32*)(u32)(uintptr_t)lds,
      16, 0, 0);
}

// RNE float -> bf16 bits
__device__ __forceinline__ u16 f2bf(float f) {
  union { float f; unsigned u; } c; c.f = f;
  unsigned u = c.u;
  unsigned r = (u + 0x7fffu + ((u >> 16) & 1u)) >> 16;
  return (u16)r;
}

// ---------------- elementwise fp32 -> bf16 ----------------
__global__ __launch_bounds__(256) void conv_bf16(const float* __restrict__ in,
                                                 u16* __restrict__ out, int n) {
  int i = (blockIdx.x * 256 + threadIdx.x) * 4;
  if (i < n) {
    float4 f = *reinterpret_cast<const float4*>(in + i);
    u16 o[4] = { f2bf(f.x), f2bf(f.y), f2bf(f.z), f2bf(f.w) };
    *reinterpret_cast<uint2*>(out + i) = *reinterpret_cast<uint2*>(o);
  }
}

// ---------------- transpose fp32 [K][N] -> bf16 [N][K] ----------------
__global__ __launch_bounds__(256) void transpose_bf16(const float* __restrict__ in,
                                                      u16* __restrict__ out,
                                                      int K, int N) {
  __shared__ float tile[32][33];
  int bi = blockIdx.y;
  int bj = blockIdx.x;
  int tx = threadIdx.x & 31;
  int ty = threadIdx.x >> 5;
#pragma unroll
  for (int i = 0; i < 4; ++i) {
    int row = ty + i * 8;
    tile[row][tx] = in[(bi * 32 + row) * N + bj * 32 + tx];
  }
  __syncthreads();
#pragma unroll
  for (int i = 0; i < 4; ++i) {
    int row = ty + i * 8;
    out[(bj * 32 + row) * K + bi * 32 + tx] = f2bf(tile[tx][row]);
  }
}

// ---------------- QKV GEMM: 128x128, BK=64, prefetched 2-phase ----------------
// 256 thr = 4 waves (2x2), per-wave C = 64x64 (acc 4x4 f32x4). LDS = 2 buf x
// (A 128x64 + B 128x64) = 64 KB -> 2 independent blocks/CU (2 waves/SIMD each,
// un-lockstepped TLP). Grid 1536 at 2/CU = 3 exact full rounds.
// Per tile: stage(next) [8 gload_lds/thread] ; vmcnt(8) [this tile landed,
// next in flight] ; barrier ; 16 ds_read_b128 + 32 MFMA ; lgkmcnt(0) ; barrier.
// Swizzle both-sides: staged global col-group (l&7)^(l>>3); ds_read col-group
// (kh*4+lq)^(lm&7)  (rows are 128B = full bank wrap, so col picks the bank).
__global__ __launch_bounds__(256, 2) void gemm_qkv(const u16* __restrict__ A,
                                                   const u16* __restrict__ Bt,
                                                   const float* __restrict__ b_attn,
                                                   const float* __restrict__ bQ,
                                                   const float* __restrict__ bK,
                                                   u16* __restrict__ qo,
                                                   u16* __restrict__ ko,
                                                   u16* __restrict__ vo) {
  const int K = C_;
  // bijective XCD swizzle: 1536 = 8 x 192; bm-major inside a chunk
  int bid = blockIdx.x;
  int wg = (bid & 7) * 192 + (bid >> 3);
  int bm = wg / 24, bn = wg % 24;

  int tid = threadIdx.x;
  int wid = tid >> 6, lane = tid & 63;
  int lm = lane & 15, lq = lane >> 4;
  int wm = (wid >> 1) * 64, wn = (wid & 1) * 64;

  __shared__ u16 As[2][128 * 64];
  __shared__ u16 Bs[2][128 * 64];

  f32x4 acc[4][4];
#pragma unroll
  for (int i = 0; i < 4; ++i)
#pragma unroll
    for (int j = 0; j < 4; ++j) acc[i][j] = (f32x4){0.f, 0.f, 0.f, 0.f};

  const u16* Ab = A + (size_t)(bm * 128) * K;
  const u16* Bb = Bt + (size_t)(bn * 128) * K;
  int srow = lane >> 3;                  // row within 8-row chunk
  int sgc  = ((lane & 7) ^ srow) * 8;    // pre-swizzled global u16 col offset

  auto stage = [&](int bb, int t) {
#pragma unroll
    for (int i = 0; i < 4; ++i) {
      int c = i * 4 + wid;               // chunk 0..15 (8 rows, 1KB each)
      async_copy16(&As[bb][c * 512], Ab + (size_t)(c * 8 + srow) * K + t * 64 + sgc);
      async_copy16(&Bs[bb][c * 512], Bb + (size_t)(c * 8 + srow) * K + t * 64 + sgc);
    }
  };

  stage(0, 0);
  const int NT = K / 64;   // 16
  for (int t = 0; t < NT; ++t) {
    int bb = t & 1;
    int tn = (t + 1 < NT) ? t + 1 : t;   // clamp keeps vmcnt counts static
    stage(bb ^ 1, tn);                   // prefetch next tile
    WAIT_VM8();                          // this tile's 8 landed; next 8 flying
    BARRIER();
    bf16x8 af[4][2], bf[4][2];
#pragma unroll
    for (int mt = 0; mt < 4; ++mt) {
      const u16* base = &As[bb][(wm + mt * 16 + lm) * 64];
#pragma unroll
      for (int kh = 0; kh < 2; ++kh)
        af[mt][kh] = *reinterpret_cast<const bf16x8*>(base + (((kh * 4 + lq) ^ (lm & 7)) * 8));
    }
#pragma unroll
    for (int nt = 0; nt < 4; ++nt) {
      const u16* base = &Bs[bb][(wn + nt * 16 + lm) * 64];
#pragma unroll
      for (int kh = 0; kh < 2; ++kh)
        bf[nt][kh] = *reinterpret_cast<const bf16x8*>(base + (((kh * 4 + lq) ^ (lm & 7)) * 8));
    }
#pragma unroll
    for (int mt = 0; mt < 4; ++mt)
#pragma unroll
      for (int nt = 0; nt < 4; ++nt)
#pragma unroll
        for (int kh = 0; kh < 2; ++kh)
          acc[mt][nt] = __builtin_amdgcn_mfma_f32_16x16x32_bf16(af[mt][kh], bf[nt][kh],
                                                                acc[mt][nt], 0, 0, 0);
    LGKM0();                // this wave's reads of buf bb done...
    BARRIER();              // ...block-wide, before next iter overwrites it
  }
  WAIT_VM0();               // drain clamped tail prefetch before exit

  const float qscale = 0.18033688011112042f;  // 1/sqrt(64) * log2(e)
#pragma unroll
  for (int mt = 0; mt < 4; ++mt) {
#pragma unroll
    for (int nt = 0; nt < 4; ++nt) {
#pragma unroll
      for (int r = 0; r < 4; ++r) {
        int m = bm * 128 + wm + mt * 16 + lq * 4 + r;
        int n = bn * 128 + wn + nt * 16 + lm;
        float val = acc[mt][nt][r] + b_attn[n];
        int sel = n >> 10;
        int c = n & 1023;
        int h = c >> 6;
        int d = c & 63;
        int b = m >> 11;
        int t = m & 2047;
        if (sel == 0)      qo[(((size_t)(b * NH_ + h) * T_) + t) * D_ + d] = f2bf((val + bQ[c]) * qscale);
        else if (sel == 1) ko[(((size_t)(b * NH_ + h) * T_) + t) * D_ + d] = f2bf(val + bK[c]);
        else               vo[(((size_t)(b * NH_ + h) * D_) + d) * T_ + t] = f2bf(val);  // transposed
      }
    }
  }
}

// ---------------- Flash attention ----------------
// R2 structure + VALU diet:
//  * lsum via ones-row PV: V^T gets a 17th..  dummy 16-row tile (row 64 = 1.0)
//    so the PV MFMA accumulates row-sums of P into o5 (removes per-entry rs
//    adds + 2 shfl-reduces/iter from the VALU pipe; +4 MFMA on the idle pipe).
//  * T13 defer-max (THR=8): skip the O-rescale unless the tile max grew by >8;
//    deferred P bounded by 2^8 (f32/bf16 safe). Rescale becomes rare.
__global__ __launch_bounds__(256, 4) void attn_kernel(const u16* __restrict__ q,
                                                      const u16* __restrict__ k,
                                                      const u16* __restrict__ vt,
                                                      u16* __restrict__ y) {
  int tid = threadIdx.x;
  int w = tid >> 6, lane = tid & 63;
  int lm = lane & 15, lq = lane >> 4;

  __shared__ u16 Ks[2][64 * 64];   // [buf][key][d swizzled]        16 KB
  __shared__ u16 Vs[2][80 * 64];   // [buf][d | dummy][key swizzled] 20 KB

  int srow = lane >> 3;            // staging row within 8-row chunk
  int sg   = (lane & 7) ^ srow;    // swizzled 16B col-group

  // dummy rows 64..79: row 64 = 1.0 (bf16), rest 0. Swizzle-invariant
  // (constant per row). Written once; staging never touches rows >= 64.
  for (int i = tid; i < 2 * 16 * 64; i += 256) {
    int bufi = i >> 10;
    int r = (i >> 6) & 15;
    int c = i & 63;
    Vs[bufi][(64 + r) * 64 + c] = (r == 0) ? (u16)0x3F80 : (u16)0;
  }
  __syncthreads();

  // static balanced mapping (LPT)
  int idx = blockIdx.x;
  int c8 = idx & 255, jq = idx >> 8;
  int a = c8 & 7, gq = c8 >> 3;
  int qt, bh;
  if (jq == 0)      { qt = 15 - a; bh = gq; }
  else if (jq == 1) { qt = 8 + a;  bh = 32 + gq; }
  else if (jq == 2) { qt = 7 - a;  bh = gq; }
  else              { qt = a;      bh = 32 + gq; }

  int b = bh >> 4, h = bh & 15;
  const int klast = 2 * qt + 1;
  const int qrow0 = qt * 128 + w * 32;

  const u16* qb = q + ((size_t)bh * T_ + qrow0) * D_;
  const u16* kb = k + (size_t)bh * T_ * D_;
  const u16* vb = vt + (size_t)bh * D_ * T_;   // [d][t]

  auto stage_K = [&](int buf, int kbi) {
    const u16* gb = kb + (size_t)(kbi * 64) * 64;
#pragma unroll
    for (int j = 0; j < 2; ++j) {
      int c = w * 2 + j;
      async_copy16(&Ks[buf][c * 512], gb + (c * 8 + srow) * 64 + sg * 8);
    }
  };
  auto stage_V = [&](int buf, int kbi) {
    const u16* gb = vb + kbi * 64;
#pragma unroll
    for (int j = 0; j < 2; ++j) {
      int c = w * 2 + j;
      async_copy16(&Vs[buf][c * 512], gb + (size_t)(c * 8 + srow) * T_ + sg * 8);
    }
  };

  // Q as B-operand: lane n=q=lm, k=d (pre-scaled by 1/sqrt(D)*log2e)
  bf16x8 bq[2][2];
#pragma unroll
  for (int qt2 = 0; qt2 < 2; ++qt2) {
    const u16* qp = qb + (qt2 * 16 + lm) * D_ + lq * 8;
    bq[qt2][0] = *reinterpret_cast<const bf16x8*>(qp);
    bq[qt2][1] = *reinterpret_cast<const bf16x8*>(qp + 32);
  }

  f32x4 o[4][2], o5[2];
#pragma unroll
  for (int dt = 0; dt < 4; ++dt)
#pragma unroll
    for (int qt2 = 0; qt2 < 2; ++qt2) o[dt][qt2] = (f32x4){0.f, 0.f, 0.f, 0.f};
  o5[0] = (f32x4){0.f, 0.f, 0.f, 0.f};
  o5[1] = (f32x4){0.f, 0.f, 0.f, 0.f};
  float mprev[2] = {-1e30f, -1e30f};

  stage_K(0, 0); stage_V(0, 0);
  stage_K(1, 1); stage_V(1, 1);

  for (int kbi = 0; kbi <= klast; ++kbi) {
    int buf = kbi & 1;
    WAIT_VM4();                  // own share of tile kbi landed (kbi+1 flying)
    BARRIER();                   // all waves' shares landed

    // K frags: row=key=kt*16+lm, swizzled col-group
    bf16x8 kf[4][2];
#pragma unroll
    for (int kt = 0; kt < 4; ++kt) {
      const u16* base = &Ks[buf][(kt * 16 + lm) * 64];
      kf[kt][0] = *reinterpret_cast<const bf16x8*>(base + ((lq ^ (lm & 7)) * 8));
      kf[kt][1] = *reinterpret_cast<const bf16x8*>(base + (((4 + lq) ^ (lm & 7)) * 8));
    }

    // S^T[key][q]: lane (q=lm, lq) element r of s[kt] -> key kt*16+lq*4+r
    f32x4 s[4][2];
#pragma unroll
    for (int kt = 0; kt < 4; ++kt)
#pragma unroll
      for (int qt2 = 0; qt2 < 2; ++qt2) {
        f32x4 z = (f32x4){0.f, 0.f, 0.f, 0.f};
        z = __builtin_amdgcn_mfma_f32_16x16x32_bf16(kf[kt][0], bq[qt2][0], z, 0, 0, 0);
        z = __builtin_amdgcn_mfma_f32_16x16x32_bf16(kf[kt][1], bq[qt2][1], z, 0, 0, 0);
        s[kt][qt2] = z;
      }

    bool maskt = (kbi * 64 + 63 > qrow0);
    bf16x8 pb[2][2];             // P as PV B-operand, natural key order
#pragma unroll
    for (int qt2 = 0; qt2 < 2; ++qt2) {
      int qg = qrow0 + qt2 * 16 + lm;
      if (maskt) {
#pragma unroll
        for (int kt = 0; kt < 4; ++kt)
#pragma unroll
          for (int r = 0; r < 4; ++r) {
            int key = kbi * 64 + kt * 16 + lq * 4 + r;
            if (key > qg) s[kt][qt2][r] = -1e30f;
          }
      }
      float mx[4];
#pragma unroll
      for (int kt = 0; kt < 4; ++kt)
        mx[kt] = fmaxf(fmaxf(s[kt][qt2][0], s[kt][qt2][1]),
                       fmaxf(s[kt][qt2][2], s[kt][qt2][3]));
      float mval = fmaxf(fmaxf(mx[0], mx[1]), fmaxf(mx[2], mx[3]));
      mval = fmaxf(mval, __shfl_xor(mval, 16));
      mval = fmaxf(mval, __shfl_xor(mval, 32));
      // T13 defer-max: rescale only when the max grew by > 8
      float mold = mprev[qt2];
      if (__ballot(mval > mold + 8.f)) {
        float mnew = fmaxf(mold, mval);
        float alpha = __builtin_exp2f(mold - mnew);
#pragma unroll
        for (int dt = 0; dt < 4; ++dt) o[dt][qt2] *= alpha;
        o5[qt2] *= alpha;
        mprev[qt2] = mnew;
      }
      float m = mprev[qt2];
      unsigned pw[8];
#pragma unroll
      for (int kt = 0; kt < 4; ++kt) {
        unsigned pu[4];
#pragma unroll
        for (int r = 0; r < 4; ++r) {
          float p = __builtin_exp2f(s[kt][qt2][r] - m);
          union { float f; unsigned u; } cc; cc.f = p;
          pu[r] = cc.u;
        }
        pw[kt * 2]     = __builtin_amdgcn_perm(pu[1], pu[0], 0x07060302u);
        pw[kt * 2 + 1] = __builtin_amdgcn_perm(pu[3], pu[2], 0x07060302u);
      }
      union { unsigned u[4]; bf16x8 v; } b0, b1;
#pragma unroll
      for (int t = 0; t < 4; ++t) { b0.u[t] = pw[t]; b1.u[t] = pw[4 + t]; }
      pb[qt2][0] = b0.v;
      pb[qt2][1] = b1.v;
    }

    // PV (+ ones-row lsum): same permuted k-slot->key map on V (A operand)
    {
      int r7 = lm & 7;
      int h4 = (lq & 1) * 4;
      int g0 = lq >> 1;
      bf16x8 v5[2];
      {
        const u16* vb5 = &Vs[buf][(64 + lm) * 64];
        union { u64 qd[2]; bf16x8 v; } t0, t1;
        t0.qd[0] = *reinterpret_cast<const u64*>(vb5 + ((g0 ^ r7) * 8) + h4);
        t0.qd[1] = *reinterpret_cast<const u64*>(vb5 + (((g0 + 2) ^ r7) * 8) + h4);
        t1.qd[0] = *reinterpret_cast<const u64*>(vb5 + (((g0 + 4) ^ r7) * 8) + h4);
        t1.qd[1] = *reinterpret_cast<const u64*>(vb5 + (((g0 + 6) ^ r7) * 8) + h4);
        v5[0] = t0.v; v5[1] = t1.v;
      }
#pragma unroll
      for (int dt = 0; dt < 4; ++dt) {
        const u16* vbase = &Vs[buf][(dt * 16 + lm) * 64];
        union { u64 qd[2]; bf16x8 v; } t0, t1;
        t0.qd[0] = *reinterpret_cast<const u64*>(vbase + ((g0 ^ r7) * 8) + h4);
        t0.qd[1] = *reinterpret_cast<const u64*>(vbase + (((g0 + 2) ^ r7) * 8) + h4);
        t1.qd[0] = *reinterpret_cast<const u64*>(vbase + (((g0 + 4) ^ r7) * 8) + h4);
        t1.qd[1] = *reinterpret_cast<const u64*>(vbase + (((g0 + 6) ^ r7) * 8) + h4);
#pragma unroll
        for (int qt2 = 0; qt2 < 2; ++qt2) {
          o[dt][qt2] = __builtin_amdgcn_mfma_f32_16x16x32_bf16(t0.v, pb[qt2][0], o[dt][qt2], 0, 0, 0);
          o[dt][qt2] = __builtin_amdgcn_mfma_f32_16x16x32_bf16(t1.v, pb[qt2][1], o[dt][qt2], 0, 0, 0);
        }
      }
#pragma unroll
      for (int qt2 = 0; qt2 < 2; ++qt2) {
        o5[qt2] = __builtin_amdgcn_mfma_f32_16x16x32_bf16(v5[0], pb[qt2][0], o5[qt2], 0, 0, 0);
        o5[qt2] = __builtin_amdgcn_mfma_f32_16x16x32_bf16(v5[1], pb[qt2][1], o5[qt2], 0, 0, 0);
      }
    }

    BARRIER();                   // all waves done reading buf before overwrite
    int nk = (kbi + 2 <= klast) ? kbi + 2 : klast;
    stage_K(buf, nk); stage_V(buf, nk);
  }

  WAIT_VM0();  // drain tail prefetches before LDS is freed at endpgm

  // write y[b][t=q][h][d]; lsum = o5 row 0 (lanes lq==0), broadcast via shfl
#pragma unroll
  for (int qt2 = 0; qt2 < 2; ++qt2) {
    float ls = __shfl(o5[qt2][0], lm);    // lane lm holds row-0 sum for q=lm
    float inv = 1.f / ls;
    int qg = qrow0 + qt2 * 16 + lm;
#pragma unroll
    for (int dt = 0; dt < 4; ++dt) {
      u16 wb[4];
#pragma unroll
      for (int r = 0; r < 4; ++r) wb[r] = f2bf(o[dt][qt2][r] * inv);
      int d = dt * 16 + lq * 4;
      *reinterpret_cast<uint2*>(&y[((size_t)(b * T_ + qg) * NH_ + h) * D_ + d]) =
          *reinterpret_cast<uint2*>(wb);
    }
  }
}

// ---------------- Proj GEMM: 128x128, BK=64, prefetched 2-phase ----------------
__global__ __launch_bounds__(256, 2) void gemm_proj(const u16* __restrict__ A,
                                                    const u16* __restrict__ Bt,
                                                    const float* __restrict__ b_proj,
                                                    float* __restrict__ out) {
  const int K = C_, N = C_;
  int bid = blockIdx.x;
  int wg = (bid & 7) * 64 + (bid >> 3);   // 512 = 8 x 64 bijective
  int bm = wg / 8, bn = wg % 8;

  int tid = threadIdx.x;
  int wid = tid >> 6, lane = tid & 63;
  int lm = lane & 15, lq = lane >> 4;
  int wm = (wid >> 1) * 64, wn = (wid & 1) * 64;

  __shared__ u16 As[2][128 * 64];
  __shared__ u16 Bs[2][128 * 64];

  f32x4 acc[4][4];
#pragma unroll
  for (int i = 0; i < 4; ++i)
#pragma unroll
    for (int j = 0; j < 4; ++j) acc[i][j] = (f32x4){0.f, 0.f, 0.f, 0.f};

  const u16* Ab = A + (size_t)(bm * 128) * K;
  const u16* Bb = Bt + (size_t)(bn * 128) * K;
  int srow = lane >> 3;
  int sgc  = ((lane & 7) ^ srow) * 8;

  auto stage = [&](int bb, int t) {
#pragma unroll
    for (int i = 0; i < 4; ++i) {
      int c = i * 4 + wid;
      async_copy16(&As[bb][c * 512], Ab + (size_t)(c * 8 + srow) * K + t * 64 + sgc);
      async_copy16(&Bs[bb][c * 512], Bb + (size_t)(c * 8 + srow) * K + t * 64 + sgc);
    }
  };

  stage(0, 0);
  const int NT = K / 64;   // 16
  for (int t = 0; t < NT; ++t) {
    int bb = t & 1;
    int tn = (t + 1 < NT) ? t + 1 : t;
    stage(bb ^ 1, tn);
    WAIT_VM8();
    BARRIER();
    bf16x8 af[4][2], bf[4][2];
#pragma unroll
    for (int mt = 0; mt < 4; ++mt) {
      const u16* base = &As[bb][(wm + mt * 16 + lm) * 64];
#pragma unroll
      for (int kh = 0; kh < 2; ++kh)
        af[mt][kh] = *reinterpret_cast<const bf16x8*>(base + (((kh * 4 + lq) ^ (lm & 7)) * 8));
    }
#pragma unroll
    for (int nt = 0; nt < 4; ++nt) {
      const u16* base = &Bs[bb][(wn + nt * 16 + lm) * 64];
#pragma unroll
      for (int kh = 0; kh < 2; ++kh)
        bf[nt][kh] = *reinterpret_cast<const bf16x8*>(base + (((kh * 4 + lq) ^ (lm & 7)) * 8));
    }
#pragma unroll
    for (int mt = 0; mt < 4; ++mt)
#pragma unroll
      for (int nt = 0; nt < 4; ++nt)
#pragma unroll
        for (int kh = 0; kh < 2; ++kh)
          acc[mt][nt] = __builtin_amdgcn_mfma_f32_16x16x32_bf16(af[mt][kh], bf[nt][kh],
                                                                acc[mt][nt], 0, 0, 0);
    LGKM0();
    BARRIER();
  }
  WAIT_VM0();

#pragma unroll
  for (int mt = 0; mt < 4; ++mt) {
#pragma unroll
    for (int nt = 0; nt < 4; ++nt) {
#pragma unroll
      for (int r = 0; r < 4; ++r) {
        int m = bm * 128 + wm + mt * 16 + lq * 4 + r;
        int n = bn * 128 + wn + nt * 16 + lm;
        out[(size_t)m * N + n] = acc[mt][nt][r] + b_proj[n];
      }
    }
  }
}

extern "C" void kernel_launch(void* const* d_in, const int* in_sizes, int n_in,
                              void* d_out, int out_size, void* d_ws, size_t ws_size,
                              hipStream_t stream) {
  const float* x      = (const float*)d_in[0];
  const float* W_attn = (const float*)d_in[1];
  const float* b_attn = (const float*)d_in[2];
  const float* bQ     = (const float*)d_in[3];
  const float* bK     = (const float*)d_in[4];
  const float* W_proj = (const float*)d_in[5];
  const float* b_proj = (const float*)d_in[6];
  float* out = (float*)d_out;

  char* ws = (char*)d_ws;
  u16* xb  = (u16*)(ws);                              // [8192][1024]      16 MB
  u16* WaT = (u16*)(ws + 16777216);                   // [3072][1024]       6 MB
  u16* WpT = (u16*)(ws + 23068672);                   // [1024][1024]       2 MB
  u16* qw  = (u16*)(ws + 25165824);                   // [B,NH,T,D] scaled 16 MB
  u16* kw  = (u16*)(ws + 41943040);                   // [B,NH,T,D]        16 MB
  u16* vw  = (u16*)(ws + 58720256);                   // [B,NH,D,T] (V^T)  16 MB
  u16* yw  = (u16*)(ws + 75497472);                   // [8192][1024]      16 MB

  conv_bf16<<<M_ * C_ / (4 * 256), 256, 0, stream>>>(x, xb, M_ * C_);
  {
    dim3 g(N_QKV / 32, C_ / 32);
    transpose_bf16<<<g, 256, 0, stream>>>(W_attn, WaT, C_, N_QKV);
  }
  {
    dim3 g(C_ / 32, C_ / 32);
    transpose_bf16<<<g, 256, 0, stream>>>(W_proj, WpT, C_, C_);
  }
  gemm_qkv<<<(M_ / 128) * (N_QKV / 128), 256, 0, stream>>>(xb, WaT, b_attn, bQ, bK, qw, kw, vw);
  attn_kernel<<<ATTN_BLOCKS, 256, 0, stream>>>(qw, kw, vw, yw);
  gemm_proj<<<(M_ / 128) * (C_ / 128), 256, 0, stream>>>(yw, WpT, b_proj, out);
}

// Round 4
// 325.739 us; speedup vs baseline: 1.0371x; 1.0371x over previous
//
#include <hip/hip_runtime.h>

typedef unsigned short u16;
typedef unsigned int u32;
typedef unsigned long long u64;
typedef __bf16 bf16x8 __attribute__((ext_vector_type(8)));
typedef float f32x4 __attribute__((ext_vector_type(4)));

#define B_  4
#define T_  2048
#define C_  1024
#define NH_ 16
#define D_  64
#define M_  (B_*T_)          // 8192
#define N_QKV (3*C_)         // 3072

#define ATTN_BLOCKS 1024     // one block per item, 4-5 blocks/CU (32KB LDS)

// raw barrier + static waitcnt (no vmcnt(0) drain -- keeps prefetch in flight)
#define BARRIER()  __asm__ __volatile__("s_barrier" ::: "memory")
#define WAIT_VM4() __asm__ __volatile__("s_waitcnt vmcnt(4)" ::: "memory")
#define WAIT_VM8() __asm__ __volatile__("s_waitcnt vmcnt(8)" ::: "memory")
#define WAIT_VM0() __asm__ __volatile__("s_waitcnt vmcnt(0)" ::: "memory")
#define LGKM0()    __asm__ __volatile__("s_waitcnt lgkmcnt(0)" ::: "memory")

// async global->LDS, 16B per lane. LDS dest = wave-uniform base + lane*16
__device__ __forceinline__ void async_copy16(void* lds, const void* gptr) {
  __builtin_amdgcn_global_load_lds(
      (const __attribute__((address_space(1))) u32*)gptr,
      (__attribute__((address_space(3))) u32*)(u32)(uintptr_t)lds,
      16, 0, 0);
}

// RNE float -> bf16 bits
__device__ __forceinline__ u16 f2bf(float f) {
  union { float f; unsigned u; } c; c.f = f;
  unsigned u = c.u;
  unsigned r = (u + 0x7fffu + ((u >> 16) & 1u)) >> 16;
  return (u16)r;
}

// ---------------- elementwise fp32 -> bf16 ----------------
__global__ __launch_bounds__(256) void conv_bf16(const float* __restrict__ in,
                                                 u16* __restrict__ out, int n) {
  int i = (blockIdx.x * 256 + threadIdx.x) * 4;
  if (i < n) {
    float4 f = *reinterpret_cast<const float4*>(in + i);
    u16 o[4] = { f2bf(f.x), f2bf(f.y), f2bf(f.z), f2bf(f.w) };
    *reinterpret_cast<uint2*>(out + i) = *reinterpret_cast<uint2*>(o);
  }
}

// ---------------- transpose fp32 [K][N] -> bf16 [N][K] ----------------
__global__ __launch_bounds__(256) void transpose_bf16(const float* __restrict__ in,
                                                      u16* __restrict__ out,
                                                      int K, int N) {
  __shared__ float tile[32][33];
  int bi = blockIdx.y;
  int bj = blockIdx.x;
  int tx = threadIdx.x & 31;
  int ty = threadIdx.x >> 5;
#pragma unroll
  for (int i = 0; i < 4; ++i) {
    int row = ty + i * 8;
    tile[row][tx] = in[(bi * 32 + row) * N + bj * 32 + tx];
  }
  __syncthreads();
#pragma unroll
  for (int i = 0; i < 4; ++i) {
    int row = ty + i * 8;
    out[(bj * 32 + row) * K + bi * 32 + tx] = f2bf(tile[tx][row]);
  }
}

// ---------------- QKV GEMM: 128x128, BK=64, prefetched 2-phase ----------------
__global__ __launch_bounds__(256, 2) void gemm_qkv(const u16* __restrict__ A,
                                                   const u16* __restrict__ Bt,
                                                   const float* __restrict__ b_attn,
                                                   const float* __restrict__ bQ,
                                                   const float* __restrict__ bK,
                                                   u16* __restrict__ qo,
                                                   u16* __restrict__ ko,
                                                   u16* __restrict__ vo) {
  const int K = C_;
  // bijective XCD swizzle: 1536 = 8 x 192; bm-major inside a chunk
  int bid = blockIdx.x;
  int wg = (bid & 7) * 192 + (bid >> 3);
  int bm = wg / 24, bn = wg % 24;

  int tid = threadIdx.x;
  int wid = tid >> 6, lane = tid & 63;
  int lm = lane & 15, lq = lane >> 4;
  int wm = (wid >> 1) * 64, wn = (wid & 1) * 64;

  __shared__ u16 As[2][128 * 64];
  __shared__ u16 Bs[2][128 * 64];

  f32x4 acc[4][4];
#pragma unroll
  for (int i = 0; i < 4; ++i)
#pragma unroll
    for (int j = 0; j < 4; ++j) acc[i][j] = (f32x4){0.f, 0.f, 0.f, 0.f};

  const u16* Ab = A + (size_t)(bm * 128) * K;
  const u16* Bb = Bt + (size_t)(bn * 128) * K;
  int srow = lane >> 3;                  // row within 8-row chunk
  int sgc  = ((lane & 7) ^ srow) * 8;    // pre-swizzled global u16 col offset

  auto stage = [&](int bb, int t) {
#pragma unroll
    for (int i = 0; i < 4; ++i) {
      int c = i * 4 + wid;               // chunk 0..15 (8 rows, 1KB each)
      async_copy16(&As[bb][c * 512], Ab + (size_t)(c * 8 + srow) * K + t * 64 + sgc);
      async_copy16(&Bs[bb][c * 512], Bb + (size_t)(c * 8 + srow) * K + t * 64 + sgc);
    }
  };

  stage(0, 0);
  const int NT = K / 64;   // 16
  for (int t = 0; t < NT; ++t) {
    int bb = t & 1;
    int tn = (t + 1 < NT) ? t + 1 : t;   // clamp keeps vmcnt counts static
    stage(bb ^ 1, tn);                   // prefetch next tile
    WAIT_VM8();                          // this tile's 8 landed; next 8 flying
    BARRIER();
    bf16x8 af[4][2], bf[4][2];
#pragma unroll
    for (int mt = 0; mt < 4; ++mt) {
      const u16* base = &As[bb][(wm + mt * 16 + lm) * 64];
#pragma unroll
      for (int kh = 0; kh < 2; ++kh)
        af[mt][kh] = *reinterpret_cast<const bf16x8*>(base + (((kh * 4 + lq) ^ (lm & 7)) * 8));
    }
#pragma unroll
    for (int nt = 0; nt < 4; ++nt) {
      const u16* base = &Bs[bb][(wn + nt * 16 + lm) * 64];
#pragma unroll
      for (int kh = 0; kh < 2; ++kh)
        bf[nt][kh] = *reinterpret_cast<const bf16x8*>(base + (((kh * 4 + lq) ^ (lm & 7)) * 8));
    }
#pragma unroll
    for (int mt = 0; mt < 4; ++mt)
#pragma unroll
      for (int nt = 0; nt < 4; ++nt)
#pragma unroll
        for (int kh = 0; kh < 2; ++kh)
          acc[mt][nt] = __builtin_amdgcn_mfma_f32_16x16x32_bf16(af[mt][kh], bf[nt][kh],
                                                                acc[mt][nt], 0, 0, 0);
    LGKM0();                // this wave's reads of buf bb done...
    BARRIER();              // ...block-wide, before next iter overwrites it
  }
  WAIT_VM0();               // drain clamped tail prefetch before exit

  const float qscale = 0.18033688011112042f;  // 1/sqrt(64) * log2(e)
#pragma unroll
  for (int mt = 0; mt < 4; ++mt) {
#pragma unroll
    for (int nt = 0; nt < 4; ++nt) {
#pragma unroll
      for (int r = 0; r < 4; ++r) {
        int m = bm * 128 + wm + mt * 16 + lq * 4 + r;
        int n = bn * 128 + wn + nt * 16 + lm;
        float val = acc[mt][nt][r] + b_attn[n];
        int sel = n >> 10;
        int c = n & 1023;
        int h = c >> 6;
        int d = c & 63;
        int b = m >> 11;
        int t = m & 2047;
        if (sel == 0)      qo[(((size_t)(b * NH_ + h) * T_) + t) * D_ + d] = f2bf((val + bQ[c]) * qscale);
        else if (sel == 1) ko[(((size_t)(b * NH_ + h) * T_) + t) * D_ + d] = f2bf(val + bK[c]);
        else               vo[(((size_t)(b * NH_ + h) * D_) + d) * T_ + t] = f2bf(val);  // transposed
      }
    }
  }
}

// ---------------- Flash attention ----------------
// R2 structure + fixed VALU diet:
//  * lsum via CONSTANT-ones A-operand MFMA: o5 = mfma(ones, pb, o5) computes
//    colsum(P) in every output row -- no LDS reads, no dummy rows, no shfl
//    reduction, epilogue reads o5[qt2][0] directly. (R3's LDS-ones regressed:
//    8 swizzled b64 reads + lgkm dependency on the per-iter critical path.)
//  * T13 defer-max (THR=8): P bounded by 2^8, rescale rare.
//  * T5 s_setprio(1) around S and PV MFMA clusters (independent blocks per
//    SIMD -> scheduler has role diversity to arbitrate).
__global__ __launch_bounds__(256, 4) void attn_kernel(const u16* __restrict__ q,
                                                      const u16* __restrict__ k,
                                                      const u16* __restrict__ vt,
                                                      u16* __restrict__ y) {
  int tid = threadIdx.x;
  int w = tid >> 6, lane = tid & 63;
  int lm = lane & 15, lq = lane >> 4;

  __shared__ u16 Ks[2][64 * 64];   // [buf][key][d swizzled]    16 KB
  __shared__ u16 Vs[2][64 * 64];   // [buf][d][key swizzled]    16 KB

  int srow = lane >> 3;            // staging row within 8-row chunk
  int sg   = (lane & 7) ^ srow;    // swizzled 16B col-group

  // static balanced mapping (LPT)
  int idx = blockIdx.x;
  int c8 = idx & 255, jq = idx >> 8;
  int a = c8 & 7, gq = c8 >> 3;
  int qt, bh;
  if (jq == 0)      { qt = 15 - a; bh = gq; }
  else if (jq == 1) { qt = 8 + a;  bh = 32 + gq; }
  else if (jq == 2) { qt = 7 - a;  bh = gq; }
  else              { qt = a;      bh = 32 + gq; }

  int b = bh >> 4, h = bh & 15;
  const int klast = 2 * qt + 1;
  const int qrow0 = qt * 128 + w * 32;

  const u16* qb = q + ((size_t)bh * T_ + qrow0) * D_;
  const u16* kb = k + (size_t)bh * T_ * D_;
  const u16* vb = vt + (size_t)bh * D_ * T_;   // [d][t]

  auto stage_K = [&](int buf, int kbi) {
    const u16* gb = kb + (size_t)(kbi * 64) * 64;
#pragma unroll
    for (int j = 0; j < 2; ++j) {
      int c = w * 2 + j;
      async_copy16(&Ks[buf][c * 512], gb + (c * 8 + srow) * 64 + sg * 8);
    }
  };
  auto stage_V = [&](int buf, int kbi) {
    const u16* gb = vb + kbi * 64;
#pragma unroll
    for (int j = 0; j < 2; ++j) {
      int c = w * 2 + j;
      async_copy16(&Vs[buf][c * 512], gb + (size_t)(c * 8 + srow) * T_ + sg * 8);
    }
  };

  // Q as B-operand: lane n=q=lm, k=d (pre-scaled by 1/sqrt(D)*log2e)
  bf16x8 bq[2][2];
#pragma unroll
  for (int qt2 = 0; qt2 < 2; ++qt2) {
    const u16* qp = qb + (qt2 * 16 + lm) * D_ + lq * 8;
    bq[qt2][0] = *reinterpret_cast<const bf16x8*>(qp);
    bq[qt2][1] = *reinterpret_cast<const bf16x8*>(qp + 32);
  }

  // constant all-ones A-frag for the colsum MFMA
  const __bf16 one_ = (__bf16)1.0f;
  const bf16x8 ones = (bf16x8){one_, one_, one_, one_, one_, one_, one_, one_};

  f32x4 o[4][2], o5[2];
#pragma unroll
  for (int dt = 0; dt < 4; ++dt)
#pragma unroll
    for (int qt2 = 0; qt2 < 2; ++qt2) o[dt][qt2] = (f32x4){0.f, 0.f, 0.f, 0.f};
  o5[0] = (f32x4){0.f, 0.f, 0.f, 0.f};
  o5[1] = (f32x4){0.f, 0.f, 0.f, 0.f};
  float mprev[2] = {-1e30f, -1e30f};

  stage_K(0, 0); stage_V(0, 0);
  stage_K(1, 1); stage_V(1, 1);

  for (int kbi = 0; kbi <= klast; ++kbi) {
    int buf = kbi & 1;
    WAIT_VM4();                  // own share of tile kbi landed (kbi+1 flying)
    BARRIER();                   // all waves' shares landed

    // K frags: row=key=kt*16+lm, swizzled col-group
    bf16x8 kf[4][2];
#pragma unroll
    for (int kt = 0; kt < 4; ++kt) {
      const u16* base = &Ks[buf][(kt * 16 + lm) * 64];
      kf[kt][0] = *reinterpret_cast<const bf16x8*>(base + ((lq ^ (lm & 7)) * 8));
      kf[kt][1] = *reinterpret_cast<const bf16x8*>(base + (((4 + lq) ^ (lm & 7)) * 8));
    }

    // S^T[key][q]: lane (q=lm, lq) element r of s[kt] -> key kt*16+lq*4+r
    f32x4 s[4][2];
    __builtin_amdgcn_s_setprio(1);
#pragma unroll
    for (int kt = 0; kt < 4; ++kt)
#pragma unroll
      for (int qt2 = 0; qt2 < 2; ++qt2) {
        f32x4 z = (f32x4){0.f, 0.f, 0.f, 0.f};
        z = __builtin_amdgcn_mfma_f32_16x16x32_bf16(kf[kt][0], bq[qt2][0], z, 0, 0, 0);
        z = __builtin_amdgcn_mfma_f32_16x16x32_bf16(kf[kt][1], bq[qt2][1], z, 0, 0, 0);
        s[kt][qt2] = z;
      }
    __builtin_amdgcn_s_setprio(0);

    bool maskt = (kbi * 64 + 63 > qrow0);
    bf16x8 pb[2][2];             // P as PV B-operand, natural key order
#pragma unroll
    for (int qt2 = 0; qt2 < 2; ++qt2) {
      int qg = qrow0 + qt2 * 16 + lm;
      if (maskt) {
#pragma unroll
        for (int kt = 0; kt < 4; ++kt)
#pragma unroll
          for (int r = 0; r < 4; ++r) {
            int key = kbi * 64 + kt * 16 + lq * 4 + r;
            if (key > qg) s[kt][qt2][r] = -1e30f;
          }
      }
      float mx[4];
#pragma unroll
      for (int kt = 0; kt < 4; ++kt)
        mx[kt] = fmaxf(fmaxf(s[kt][qt2][0], s[kt][qt2][1]),
                       fmaxf(s[kt][qt2][2], s[kt][qt2][3]));
      float mval = fmaxf(fmaxf(mx[0], mx[1]), fmaxf(mx[2], mx[3]));
      mval = fmaxf(mval, __shfl_xor(mval, 16));
      mval = fmaxf(mval, __shfl_xor(mval, 32));
      // T13 defer-max: rescale only when the max grew by > 8
      float mold = mprev[qt2];
      if (__ballot(mval > mold + 8.f)) {
        float mnew = fmaxf(mold, mval);
        float alpha = __builtin_exp2f(mold - mnew);
#pragma unroll
        for (int dt = 0; dt < 4; ++dt) o[dt][qt2] *= alpha;
        o5[qt2] *= alpha;
        mprev[qt2] = mnew;
      }
      float m = mprev[qt2];
      unsigned pw[8];
#pragma unroll
      for (int kt = 0; kt < 4; ++kt) {
        unsigned pu[4];
#pragma unroll
        for (int r = 0; r < 4; ++r) {
          float p = __builtin_exp2f(s[kt][qt2][r] - m);
          union { float f; unsigned u; } cc; cc.f = p;
          pu[r] = cc.u;
        }
        pw[kt * 2]     = __builtin_amdgcn_perm(pu[1], pu[0], 0x07060302u);
        pw[kt * 2 + 1] = __builtin_amdgcn_perm(pu[3], pu[2], 0x07060302u);
      }
      union { unsigned u[4]; bf16x8 v; } b0, b1;
#pragma unroll
      for (int t = 0; t < 4; ++t) { b0.u[t] = pw[t]; b1.u[t] = pw[4 + t]; }
      pb[qt2][0] = b0.v;
      pb[qt2][1] = b1.v;
    }

    // PV (+ const-ones colsum): same permuted k-slot->key map on V (A operand)
    {
      int r7 = lm & 7;
      int h4 = (lq & 1) * 4;
      int g0 = lq >> 1;
#pragma unroll
      for (int dt = 0; dt < 4; ++dt) {
        const u16* vbase = &Vs[buf][(dt * 16 + lm) * 64];
        union { u64 qd[2]; bf16x8 v; } t0, t1;
        t0.qd[0] = *reinterpret_cast<const u64*>(vbase + ((g0 ^ r7) * 8) + h4);
        t0.qd[1] = *reinterpret_cast<const u64*>(vbase + (((g0 + 2) ^ r7) * 8) + h4);
        t1.qd[0] = *reinterpret_cast<const u64*>(vbase + (((g0 + 4) ^ r7) * 8) + h4);
        t1.qd[1] = *reinterpret_cast<const u64*>(vbase + (((g0 + 6) ^ r7) * 8) + h4);
        __builtin_amdgcn_s_setprio(1);
#pragma unroll
        for (int qt2 = 0; qt2 < 2; ++qt2) {
          o[dt][qt2] = __builtin_amdgcn_mfma_f32_16x16x32_bf16(t0.v, pb[qt2][0], o[dt][qt2], 0, 0, 0);
          o[dt][qt2] = __builtin_amdgcn_mfma_f32_16x16x32_bf16(t1.v, pb[qt2][1], o[dt][qt2], 0, 0, 0);
        }
        __builtin_amdgcn_s_setprio(0);
      }
#pragma unroll
      for (int qt2 = 0; qt2 < 2; ++qt2) {
        o5[qt2] = __builtin_amdgcn_mfma_f32_16x16x32_bf16(ones, pb[qt2][0], o5[qt2], 0, 0, 0);
        o5[qt2] = __builtin_amdgcn_mfma_f32_16x16x32_bf16(ones, pb[qt2][1], o5[qt2], 0, 0, 0);
      }
    }

    BARRIER();                   // all waves done reading buf before overwrite
    int nk = (kbi + 2 <= klast) ? kbi + 2 : klast;
    stage_K(buf, nk); stage_V(buf, nk);
  }

  WAIT_VM0();  // drain tail prefetches before LDS is freed at endpgm

  // write y[b][t=q][h][d]; every o5 row holds colsum(P) for col=q=lm, so
  // lsum = o5[qt2][0] in every lane -- no shuffle needed.
#pragma unroll
  for (int qt2 = 0; qt2 < 2; ++qt2) {
    float inv = 1.f / o5[qt2][0];
    int qg = qrow0 + qt2 * 16 + lm;
#pragma unroll
    for (int dt = 0; dt < 4; ++dt) {
      u16 wb[4];
#pragma unroll
      for (int r = 0; r < 4; ++r) wb[r] = f2bf(o[dt][qt2][r] * inv);
      int d = dt * 16 + lq * 4;
      *reinterpret_cast<uint2*>(&y[((size_t)(b * T_ + qg) * NH_ + h) * D_ + d]) =
          *reinterpret_cast<uint2*>(wb);
    }
  }
}

// ---------------- Proj GEMM: 128x128, BK=64, prefetched 2-phase ----------------
__global__ __launch_bounds__(256, 2) void gemm_proj(const u16* __restrict__ A,
                                                    const u16* __restrict__ Bt,
                                                    const float* __restrict__ b_proj,
                                                    float* __restrict__ out) {
  const int K = C_, N = C_;
  int bid = blockIdx.x;
  int wg = (bid & 7) * 64 + (bid >> 3);   // 512 = 8 x 64 bijective
  int bm = wg / 8, bn = wg % 8;

  int tid = threadIdx.x;
  int wid = tid >> 6, lane = tid & 63;
  int lm = lane & 15, lq = lane >> 4;
  int wm = (wid >> 1) * 64, wn = (wid & 1) * 64;

  __shared__ u16 As[2][128 * 64];
  __shared__ u16 Bs[2][128 * 64];

  f32x4 acc[4][4];
#pragma unroll
  for (int i = 0; i < 4; ++i)
#pragma unroll
    for (int j = 0; j < 4; ++j) acc[i][j] = (f32x4){0.f, 0.f, 0.f, 0.f};

  const u16* Ab = A + (size_t)(bm * 128) * K;
  const u16* Bb = Bt + (size_t)(bn * 128) * K;
  int srow = lane >> 3;
  int sgc  = ((lane & 7) ^ srow) * 8;

  auto stage = [&](int bb, int t) {
#pragma unroll
    for (int i = 0; i < 4; ++i) {
      int c = i * 4 + wid;
      async_copy16(&As[bb][c * 512], Ab + (size_t)(c * 8 + srow) * K + t * 64 + sgc);
      async_copy16(&Bs[bb][c * 512], Bb + (size_t)(c * 8 + srow) * K + t * 64 + sgc);
    }
  };

  stage(0, 0);
  const int NT = K / 64;   // 16
  for (int t = 0; t < NT; ++t) {
    int bb = t & 1;
    int tn = (t + 1 < NT) ? t + 1 : t;
    stage(bb ^ 1, tn);
    WAIT_VM8();
    BARRIER();
    bf16x8 af[4][2], bf[4][2];
#pragma unroll
    for (int mt = 0; mt < 4; ++mt) {
      const u16* base = &As[bb][(wm + mt * 16 + lm) * 64];
#pragma unroll
      for (int kh = 0; kh < 2; ++kh)
        af[mt][kh] = *reinterpret_cast<const bf16x8*>(base + (((kh * 4 + lq) ^ (lm & 7)) * 8));
    }
#pragma unroll
    for (int nt = 0; nt < 4; ++nt) {
      const u16* base = &Bs[bb][(wn + nt * 16 + lm) * 64];
#pragma unroll
      for (int kh = 0; kh < 2; ++kh)
        bf[nt][kh] = *reinterpret_cast<const bf16x8*>(base + (((kh * 4 + lq) ^ (lm & 7)) * 8));
    }
#pragma unroll
    for (int mt = 0; mt < 4; ++mt)
#pragma unroll
      for (int nt = 0; nt < 4; ++nt)
#pragma unroll
        for (int kh = 0; kh < 2; ++kh)
          acc[mt][nt] = __builtin_amdgcn_mfma_f32_16x16x32_bf16(af[mt][kh], bf[nt][kh],
                                                                acc[mt][nt], 0, 0, 0);
    LGKM0();
    BARRIER();
  }
  WAIT_VM0();

#pragma unroll
  for (int mt = 0; mt < 4; ++mt) {
#pragma unroll
    for (int nt = 0; nt < 4; ++nt) {
#pragma unroll
      for (int r = 0; r < 4; ++r) {
        int m = bm * 128 + wm + mt * 16 + lq * 4 + r;
        int n = bn * 128 + wn + nt * 16 + lm;
        out[(size_t)m * N + n] = acc[mt][nt][r] + b_proj[n];
      }
    }
  }
}

extern "C" void kernel_launch(void* const* d_in, const int* in_sizes, int n_in,
                              void* d_out, int out_size, void* d_ws, size_t ws_size,
                              hipStream_t stream) {
  const float* x      = (const float*)d_in[0];
  const float* W_attn = (const float*)d_in[1];
  const float* b_attn = (const float*)d_in[2];
  const float* bQ     = (const float*)d_in[3];
  const float* bK     = (const float*)d_in[4];
  const float* W_proj = (const float*)d_in[5];
  const float* b_proj = (const float*)d_in[6];
  float* out = (float*)d_out;

  char* ws = (char*)d_ws;
  u16* xb  = (u16*)(ws);                              // [8192][1024]      16 MB
  u16* WaT = (u16*)(ws + 16777216);                   // [3072][1024]       6 MB
  u16* WpT = (u16*)(ws + 23068672);                   // [1024][1024]       2 MB
  u16* qw  = (u16*)(ws + 25165824);                   // [B,NH,T,D] scaled 16 MB
  u16* kw  = (u16*)(ws + 41943040);                   // [B,NH,T,D]        16 MB
  u16* vw  = (u16*)(ws + 58720256);                   // [B,NH,D,T] (V^T)  16 MB
  u16* yw  = (u16*)(ws + 75497472);                   // [8192][1024]      16 MB

  conv_bf16<<<M_ * C_ / (4 * 256), 256, 0, stream>>>(x, xb, M_ * C_);
  {
    dim3 g(N_QKV / 32, C_ / 32);
    transpose_bf16<<<g, 256, 0, stream>>>(W_attn, WaT, C_, N_QKV);
  }
  {
    dim3 g(C_ / 32, C_ / 32);
    transpose_bf16<<<g, 256, 0, stream>>>(W_proj, WpT, C_, C_);
  }
  gemm_qkv<<<(M_ / 128) * (N_QKV / 128), 256, 0, stream>>>(xb, WaT, b_attn, bQ, bK, qw, kw, vw);
  attn_kernel<<<ATTN_BLOCKS, 256, 0, stream>>>(qw, kw, vw, yw);
  gemm_proj<<<(M_ / 128) * (C_ / 128), 256, 0, stream>>>(yw, WpT, b_proj, out);
}